// Round 1
// baseline (1866.580 us; speedup 1.0000x reference)
//
#include <hip/hip_runtime.h>

#define N_NODES 100000
#define EDGES   1600000
#define CH      128
#define BN_EPS  1e-5f

// ---------------------------------------------------------------------------
// degree: deg[dst] += 1 per edge (self-loop +1 added in dinv kernel)
// ---------------------------------------------------------------------------
__global__ __launch_bounds__(256) void deg_kernel(const int* __restrict__ dst,
                                                  float* __restrict__ deg) {
    int e = blockIdx.x * 256 + threadIdx.x;
    if (e < EDGES) atomicAdd(&deg[dst[e]], 1.0f);
}

__global__ __launch_bounds__(256) void dinv_kernel(const float* __restrict__ deg,
                                                   float* __restrict__ dinv) {
    int n = blockIdx.x * 256 + threadIdx.x;
    if (n < N_NODES) dinv[n] = rsqrtf(deg[n] + 1.0f);
}

// ---------------------------------------------------------------------------
// GEMM: out[n][c] = sum_k in[n][k] * W[k][c],  [N,128] x [128,128]
// block = 256 threads, 32 rows/block, each thread 4 rows x 4 cols.
// x tile in LDS (16 KB); W rows streamed from global (L2-resident, 64 KB).
// ---------------------------------------------------------------------------
__device__ __forceinline__ void fma4(float4& acc, float a, const float4& w) {
    acc.x += a * w.x; acc.y += a * w.y; acc.z += a * w.z; acc.w += a * w.w;
}

__global__ __launch_bounds__(256) void gemm128(const float* __restrict__ in,
                                               const float* __restrict__ W,
                                               float* __restrict__ out) {
    __shared__ float4 xs[32 * 32];          // 32 rows x 128 cols as float4
    const int row0 = blockIdx.x * 32;
    const int t = threadIdx.x;

    const float4* in4 = (const float4*)(in + (size_t)row0 * CH);
    #pragma unroll
    for (int i = 0; i < 4; ++i) xs[t + i * 256] = in4[t + i * 256];
    __syncthreads();

    const int cg = t & 31;   // col group: cols 4*cg .. 4*cg+3
    const int rg = t >> 5;   // row group: rows 4*rg .. 4*rg+3
    const float4* W4 = (const float4*)W;    // W4[k*32 + cg]

    float4 acc0 = make_float4(0.f, 0.f, 0.f, 0.f);
    float4 acc1 = make_float4(0.f, 0.f, 0.f, 0.f);
    float4 acc2 = make_float4(0.f, 0.f, 0.f, 0.f);
    float4 acc3 = make_float4(0.f, 0.f, 0.f, 0.f);

    #pragma unroll 4
    for (int k4 = 0; k4 < 32; ++k4) {
        float4 a0 = xs[(rg * 4 + 0) * 32 + k4];
        float4 a1 = xs[(rg * 4 + 1) * 32 + k4];
        float4 a2 = xs[(rg * 4 + 2) * 32 + k4];
        float4 a3 = xs[(rg * 4 + 3) * 32 + k4];
        float4 w0 = W4[(k4 * 4 + 0) * 32 + cg];
        float4 w1 = W4[(k4 * 4 + 1) * 32 + cg];
        float4 w2 = W4[(k4 * 4 + 2) * 32 + cg];
        float4 w3 = W4[(k4 * 4 + 3) * 32 + cg];
        fma4(acc0, a0.x, w0); fma4(acc0, a0.y, w1); fma4(acc0, a0.z, w2); fma4(acc0, a0.w, w3);
        fma4(acc1, a1.x, w0); fma4(acc1, a1.y, w1); fma4(acc1, a1.z, w2); fma4(acc1, a1.w, w3);
        fma4(acc2, a2.x, w0); fma4(acc2, a2.y, w1); fma4(acc2, a2.z, w2); fma4(acc2, a2.w, w3);
        fma4(acc3, a3.x, w0); fma4(acc3, a3.y, w1); fma4(acc3, a3.z, w2); fma4(acc3, a3.w, w3);
    }

    float4* o0 = (float4*)(out + (size_t)(row0 + rg * 4 + 0) * CH);
    float4* o1 = (float4*)(out + (size_t)(row0 + rg * 4 + 1) * CH);
    float4* o2 = (float4*)(out + (size_t)(row0 + rg * 4 + 2) * CH);
    float4* o3 = (float4*)(out + (size_t)(row0 + rg * 4 + 3) * CH);
    o0[cg] = acc0; o1[cg] = acc1; o2[cg] = acc2; o3[cg] = acc3;
}

// ---------------------------------------------------------------------------
// agg init with self-loop: agg[n][c] = h[n][c] * dinv[n]^2   (float4 over N*32)
// ---------------------------------------------------------------------------
__global__ __launch_bounds__(256) void init_agg(const float* __restrict__ h,
                                                const float* __restrict__ dinv,
                                                float* __restrict__ agg) {
    int i = blockIdx.x * 256 + threadIdx.x;      // float4 index, N*32 total
    int n = i >> 5;
    float d = dinv[n]; d = d * d;
    float4 v = ((const float4*)h)[i];
    v.x *= d; v.y *= d; v.z *= d; v.w *= d;
    ((float4*)agg)[i] = v;
}

// ---------------------------------------------------------------------------
// edge scatter: agg[dst][c] += h[src][c] * dinv[src]*dinv[dst]
// 2 edges per 256-thread block; 128 threads per edge (one channel each)
// ---------------------------------------------------------------------------
__global__ __launch_bounds__(256) void scatter_kernel(const float* __restrict__ h,
                                                      const int* __restrict__ src,
                                                      const int* __restrict__ dst,
                                                      const float* __restrict__ dinv,
                                                      float* __restrict__ agg) {
    int e = blockIdx.x * 2 + (threadIdx.x >> 7);
    int c = threadIdx.x & 127;
    int s = src[e];
    int d = dst[e];
    float norm = dinv[s] * dinv[d];
    float v = h[(size_t)s * CH + c] * norm;
    atomicAdd(&agg[(size_t)d * CH + c], v);
}

// ---------------------------------------------------------------------------
// BN stats: per-channel sum and sum-of-squares over nodes
// ---------------------------------------------------------------------------
__global__ __launch_bounds__(256) void bn_stats(const float* __restrict__ v,
                                                float* __restrict__ gsum,
                                                float* __restrict__ gsumsq) {
    int c = threadIdx.x & 127;
    int half = threadIdx.x >> 7;
    float s = 0.f, ss = 0.f;
    for (int n = blockIdx.x * 2 + half; n < N_NODES; n += gridDim.x * 2) {
        float x = v[(size_t)n * CH + c];
        s += x; ss += x * x;
    }
    atomicAdd(&gsum[c], s);
    atomicAdd(&gsumsq[c], ss);
}

__global__ void bn_final(const float* __restrict__ gsum,
                         const float* __restrict__ gsumsq,
                         const float* __restrict__ gamma,
                         const float* __restrict__ beta,
                         float* __restrict__ scale,
                         float* __restrict__ shift) {
    int c = threadIdx.x;   // 128 threads
    const float invN = 1.0f / (float)N_NODES;
    float mu = gsum[c] * invN;
    float var = gsumsq[c] * invN - mu * mu;
    float sc = gamma[c] * rsqrtf(var + BN_EPS);
    scale[c] = sc;
    shift[c] = beta[c] - mu * sc;
}

// ---------------------------------------------------------------------------
// BN apply + relu :  out = relu(v*scale + shift)       (float4 over N*32)
// ---------------------------------------------------------------------------
__global__ __launch_bounds__(256) void bn_apply_relu(const float* __restrict__ v,
                                                     const float* __restrict__ scale,
                                                     const float* __restrict__ shift,
                                                     float* __restrict__ outv) {
    int i = blockIdx.x * 256 + threadIdx.x;
    int cg = i & 31;
    float4 a = ((const float4*)v)[i];
    float4 sc = ((const float4*)scale)[cg];
    float4 sh = ((const float4*)shift)[cg];
    a.x = fmaxf(fmaf(a.x, sc.x, sh.x), 0.f);
    a.y = fmaxf(fmaf(a.y, sc.y, sh.y), 0.f);
    a.z = fmaxf(fmaf(a.z, sc.z, sh.z), 0.f);
    a.w = fmaxf(fmaf(a.w, sc.w, sh.w), 0.f);
    ((float4*)outv)[i] = a;
}

// BN apply + residual + relu : out = relu(v*scale + shift + x)
__global__ __launch_bounds__(256) void bn_apply_res_relu(const float* __restrict__ v,
                                                         const float* __restrict__ scale,
                                                         const float* __restrict__ shift,
                                                         const float* __restrict__ xin,
                                                         float* __restrict__ outv) {
    int i = blockIdx.x * 256 + threadIdx.x;
    int cg = i & 31;
    float4 a = ((const float4*)v)[i];
    float4 r = ((const float4*)xin)[i];
    float4 sc = ((const float4*)scale)[cg];
    float4 sh = ((const float4*)shift)[cg];
    a.x = fmaxf(fmaf(a.x, sc.x, sh.x) + r.x, 0.f);
    a.y = fmaxf(fmaf(a.y, sc.y, sh.y) + r.y, 0.f);
    a.z = fmaxf(fmaf(a.z, sc.z, sh.z) + r.z, 0.f);
    a.w = fmaxf(fmaf(a.w, sc.w, sh.w) + r.w, 0.f);
    ((float4*)outv)[i] = a;
}

// ---------------------------------------------------------------------------
extern "C" void kernel_launch(void* const* d_in, const int* in_sizes, int n_in,
                              void* d_out, int out_size, void* d_ws, size_t ws_size,
                              hipStream_t stream) {
    const float* x      = (const float*)d_in[0];
    const float* W1     = (const float*)d_in[1];
    // d_in[2] = b1 : cancels exactly inside BatchNorm (per-channel constant shift)
    const float* W2     = (const float*)d_in[3];
    // d_in[4] = b2 : cancels likewise
    const float* gamma2 = (const float*)d_in[5];
    const float* beta2  = (const float*)d_in[6];
    const int*   ei     = (const int*)d_in[7];    // [2, E] int32
    const int*   srcI   = ei;
    const int*   dstI   = ei + EDGES;
    float* out = (float*)d_out;

    char* ws = (char*)d_ws;
    float* A      = (float*)(ws);                      // 51.2 MB
    float* B      = (float*)(ws + 51200000);           // 51.2 MB
    float* deg    = (float*)(ws + 102400000);          // 400 KB
    float* dinv   = (float*)(ws + 102800000);          // 400 KB
    float* gsum   = (float*)(ws + 103200000);          // 128 f
    float* gsumsq = gsum + 128;
    float* scale  = gsum + 256;
    float* shift  = gsum + 384;

    const int ELEM4_BLOCKS = (N_NODES * 32) / 256;     // 12500, exact
    const int GEMM_BLOCKS  = N_NODES / 32;             // 3125, exact

    // degree + dinv (shared by both convs)
    hipMemsetAsync(deg, 0, N_NODES * sizeof(float), stream);
    deg_kernel<<<EDGES / 256, 256, 0, stream>>>(dstI, deg);
    dinv_kernel<<<(N_NODES + 255) / 256, 256, 0, stream>>>(deg, dinv);

    // ---- conv1 ----
    gemm128<<<GEMM_BLOCKS, 256, 0, stream>>>(x, W1, A);            // h1 -> A
    init_agg<<<ELEM4_BLOCKS, 256, 0, stream>>>(A, dinv, B);        // agg1 -> B
    scatter_kernel<<<EDGES / 2, 256, 0, stream>>>(A, srcI, dstI, dinv, B);
    hipMemsetAsync(gsum, 0, 256 * sizeof(float), stream);
    bn_stats<<<256, 256, 0, stream>>>(B, gsum, gsumsq);
    bn_final<<<1, 128, 0, stream>>>(gsum, gsumsq, gamma2, beta2, scale, shift);
    bn_apply_relu<<<ELEM4_BLOCKS, 256, 0, stream>>>(B, scale, shift, A);  // x1 -> A

    // ---- conv2 ----
    gemm128<<<GEMM_BLOCKS, 256, 0, stream>>>(A, W2, B);            // h2 -> B
    init_agg<<<ELEM4_BLOCKS, 256, 0, stream>>>(B, dinv, A);        // agg2 -> A
    scatter_kernel<<<EDGES / 2, 256, 0, stream>>>(B, srcI, dstI, dinv, A);
    hipMemsetAsync(gsum, 0, 256 * sizeof(float), stream);
    bn_stats<<<256, 256, 0, stream>>>(A, gsum, gsumsq);
    bn_final<<<1, 128, 0, stream>>>(gsum, gsumsq, gamma2, beta2, scale, shift);
    bn_apply_res_relu<<<ELEM4_BLOCKS, 256, 0, stream>>>(A, scale, shift, x, out);
}

// Round 2
// 855.037 us; speedup vs baseline: 2.1830x; 2.1830x over previous
//
#include <hip/hip_runtime.h>

#define N_NODES 100000
#define EDGES   1600000
#define CH      128
#define BN_EPS  1e-5f
#define SCAN_NB ((N_NODES + 255) / 256)   // 391 scan blocks

// ---------------------------------------------------------------------------
// degree count (int) per dst
// ---------------------------------------------------------------------------
__global__ __launch_bounds__(256) void deg_kernel(const int* __restrict__ dst,
                                                  int* __restrict__ degcnt) {
    int e = blockIdx.x * 256 + threadIdx.x;
    if (e < EDGES) atomicAdd(&degcnt[dst[e]], 1);
}

__global__ __launch_bounds__(256) void dinv_kernel(const int* __restrict__ degcnt,
                                                   float* __restrict__ dinv) {
    int n = blockIdx.x * 256 + threadIdx.x;
    if (n < N_NODES) dinv[n] = rsqrtf((float)degcnt[n] + 1.0f);
}

// ---------------------------------------------------------------------------
// 3-kernel exclusive prefix scan of degcnt -> rowptr  (N = 100000)
// ---------------------------------------------------------------------------
__global__ __launch_bounds__(256) void scan1(const int* __restrict__ degcnt,
                                             int* __restrict__ rowptr,
                                             int* __restrict__ blocksum) {
    __shared__ int sh[2][256];
    int t = threadIdx.x;
    int i = blockIdx.x * 256 + t;
    int v = (i < N_NODES) ? degcnt[i] : 0;
    sh[0][t] = v;
    __syncthreads();
    int pp = 0;
    #pragma unroll
    for (int off = 1; off < 256; off <<= 1) {
        int val = sh[pp][t] + ((t >= off) ? sh[pp][t - off] : 0);
        sh[1 - pp][t] = val;
        pp = 1 - pp;
        __syncthreads();
    }
    int incl = sh[pp][t];
    if (i < N_NODES) rowptr[i] = incl - v;          // block-local exclusive
    if (t == 255) blocksum[blockIdx.x] = incl;
}

__global__ __launch_bounds__(512) void scan2(int* __restrict__ blocksum) {
    __shared__ int sh[2][512];
    int t = threadIdx.x;
    int v = (t < SCAN_NB) ? blocksum[t] : 0;
    sh[0][t] = v;
    __syncthreads();
    int pp = 0;
    #pragma unroll
    for (int off = 1; off < 512; off <<= 1) {
        int val = sh[pp][t] + ((t >= off) ? sh[pp][t - off] : 0);
        sh[1 - pp][t] = val;
        pp = 1 - pp;
        __syncthreads();
    }
    if (t < SCAN_NB) blocksum[t] = sh[pp][t] - v;   // exclusive
}

// add block offsets; also init cursor = rowptr and set rowptr[N] = E
__global__ __launch_bounds__(256) void scan3(int* __restrict__ rowptr,
                                             const int* __restrict__ blocksum,
                                             int* __restrict__ cursor) {
    int i = blockIdx.x * 256 + threadIdx.x;
    if (i < N_NODES) {
        int v = rowptr[i] + blocksum[blockIdx.x];
        rowptr[i] = v;
        cursor[i] = v;
    }
    if (i == N_NODES - 1) rowptr[N_NODES] = EDGES;
}

// bucket edges by dst: srcs[pos] = src
__global__ __launch_bounds__(256) void bucket_kernel(const int* __restrict__ src,
                                                     const int* __restrict__ dst,
                                                     int* __restrict__ cursor,
                                                     int* __restrict__ srcs) {
    int e = blockIdx.x * 256 + threadIdx.x;
    if (e < EDGES) {
        int pos = atomicAdd(&cursor[dst[e]], 1);
        srcs[pos] = src[e];
    }
}

// ---------------------------------------------------------------------------
// GEMM with dinv epilogue: out[n][c] = dinv[n] * sum_k in[n][k] * W[k][c]
// ---------------------------------------------------------------------------
__device__ __forceinline__ void fma4(float4& acc, float a, const float4& w) {
    acc.x += a * w.x; acc.y += a * w.y; acc.z += a * w.z; acc.w += a * w.w;
}
__device__ __forceinline__ void scale4(float4& a, float s) {
    a.x *= s; a.y *= s; a.z *= s; a.w *= s;
}

__global__ __launch_bounds__(256) void gemm128(const float* __restrict__ in,
                                               const float* __restrict__ W,
                                               const float* __restrict__ dinv,
                                               float* __restrict__ out) {
    __shared__ float4 xs[32 * 32];          // 32 rows x 128 cols as float4
    const int row0 = blockIdx.x * 32;
    const int t = threadIdx.x;

    const float4* in4 = (const float4*)(in + (size_t)row0 * CH);
    #pragma unroll
    for (int i = 0; i < 4; ++i) xs[t + i * 256] = in4[t + i * 256];
    __syncthreads();

    const int cg = t & 31;
    const int rg = t >> 5;
    const float4* W4 = (const float4*)W;

    float4 acc0 = make_float4(0.f, 0.f, 0.f, 0.f);
    float4 acc1 = make_float4(0.f, 0.f, 0.f, 0.f);
    float4 acc2 = make_float4(0.f, 0.f, 0.f, 0.f);
    float4 acc3 = make_float4(0.f, 0.f, 0.f, 0.f);

    #pragma unroll 4
    for (int k4 = 0; k4 < 32; ++k4) {
        float4 a0 = xs[(rg * 4 + 0) * 32 + k4];
        float4 a1 = xs[(rg * 4 + 1) * 32 + k4];
        float4 a2 = xs[(rg * 4 + 2) * 32 + k4];
        float4 a3 = xs[(rg * 4 + 3) * 32 + k4];
        float4 w0 = W4[(k4 * 4 + 0) * 32 + cg];
        float4 w1 = W4[(k4 * 4 + 1) * 32 + cg];
        float4 w2 = W4[(k4 * 4 + 2) * 32 + cg];
        float4 w3 = W4[(k4 * 4 + 3) * 32 + cg];
        fma4(acc0, a0.x, w0); fma4(acc0, a0.y, w1); fma4(acc0, a0.z, w2); fma4(acc0, a0.w, w3);
        fma4(acc1, a1.x, w0); fma4(acc1, a1.y, w1); fma4(acc1, a1.z, w2); fma4(acc1, a1.w, w3);
        fma4(acc2, a2.x, w0); fma4(acc2, a2.y, w1); fma4(acc2, a2.z, w2); fma4(acc2, a2.w, w3);
        fma4(acc3, a3.x, w0); fma4(acc3, a3.y, w1); fma4(acc3, a3.z, w2); fma4(acc3, a3.w, w3);
    }

    scale4(acc0, dinv[row0 + rg * 4 + 0]);
    scale4(acc1, dinv[row0 + rg * 4 + 1]);
    scale4(acc2, dinv[row0 + rg * 4 + 2]);
    scale4(acc3, dinv[row0 + rg * 4 + 3]);

    ((float4*)(out + (size_t)(row0 + rg * 4 + 0) * CH))[cg] = acc0;
    ((float4*)(out + (size_t)(row0 + rg * 4 + 1) * CH))[cg] = acc1;
    ((float4*)(out + (size_t)(row0 + rg * 4 + 2) * CH))[cg] = acc2;
    ((float4*)(out + (size_t)(row0 + rg * 4 + 3) * CH))[cg] = acc3;
}

// ---------------------------------------------------------------------------
// pull-gather aggregation: agg[n][c] = dinv[n] * (hs[n][c] + sum_j hs[srcs[j]][c])
// 2 nodes per 256-thread block, one channel per thread, 4-wide unrolled MLP
// ---------------------------------------------------------------------------
__global__ __launch_bounds__(256) void gather_agg(const float* __restrict__ hs,
                                                  const int* __restrict__ srcs,
                                                  const int* __restrict__ rowptr,
                                                  const float* __restrict__ dinv,
                                                  float* __restrict__ agg) {
    int n = blockIdx.x * 2 + (threadIdx.x >> 7);
    int c = threadIdx.x & 127;
    int beg = rowptr[n];
    int end = rowptr[n + 1];
    float acc = hs[(size_t)n * CH + c];            // self-loop term
    int j = beg;
    for (; j + 4 <= end; j += 4) {
        int s0 = srcs[j + 0];
        int s1 = srcs[j + 1];
        int s2 = srcs[j + 2];
        int s3 = srcs[j + 3];
        float v0 = hs[(size_t)s0 * CH + c];
        float v1 = hs[(size_t)s1 * CH + c];
        float v2 = hs[(size_t)s2 * CH + c];
        float v3 = hs[(size_t)s3 * CH + c];
        acc += (v0 + v1) + (v2 + v3);
    }
    for (; j < end; ++j) acc += hs[(size_t)srcs[j] * CH + c];
    agg[(size_t)n * CH + c] = acc * dinv[n];
}

// ---------------------------------------------------------------------------
// BatchNorm pieces
// ---------------------------------------------------------------------------
__global__ __launch_bounds__(256) void bn_stats(const float* __restrict__ v,
                                                float* __restrict__ gsum,
                                                float* __restrict__ gsumsq) {
    int c = threadIdx.x & 127;
    int half = threadIdx.x >> 7;
    float s = 0.f, ss = 0.f;
    for (int n = blockIdx.x * 2 + half; n < N_NODES; n += gridDim.x * 2) {
        float x = v[(size_t)n * CH + c];
        s += x; ss += x * x;
    }
    atomicAdd(&gsum[c], s);
    atomicAdd(&gsumsq[c], ss);
}

__global__ void bn_final(const float* __restrict__ gsum,
                         const float* __restrict__ gsumsq,
                         const float* __restrict__ gamma,
                         const float* __restrict__ beta,
                         float* __restrict__ scale,
                         float* __restrict__ shift) {
    int c = threadIdx.x;
    const float invN = 1.0f / (float)N_NODES;
    float mu = gsum[c] * invN;
    float var = gsumsq[c] * invN - mu * mu;
    float sc = gamma[c] * rsqrtf(var + BN_EPS);
    scale[c] = sc;
    shift[c] = beta[c] - mu * sc;
}

__global__ __launch_bounds__(256) void bn_apply_relu(const float* __restrict__ v,
                                                     const float* __restrict__ scale,
                                                     const float* __restrict__ shift,
                                                     float* __restrict__ outv) {
    int i = blockIdx.x * 256 + threadIdx.x;
    int cg = i & 31;
    float4 a = ((const float4*)v)[i];
    float4 sc = ((const float4*)scale)[cg];
    float4 sh = ((const float4*)shift)[cg];
    a.x = fmaxf(fmaf(a.x, sc.x, sh.x), 0.f);
    a.y = fmaxf(fmaf(a.y, sc.y, sh.y), 0.f);
    a.z = fmaxf(fmaf(a.z, sc.z, sh.z), 0.f);
    a.w = fmaxf(fmaf(a.w, sc.w, sh.w), 0.f);
    ((float4*)outv)[i] = a;
}

__global__ __launch_bounds__(256) void bn_apply_res_relu(const float* __restrict__ v,
                                                         const float* __restrict__ scale,
                                                         const float* __restrict__ shift,
                                                         const float* __restrict__ xin,
                                                         float* __restrict__ outv) {
    int i = blockIdx.x * 256 + threadIdx.x;
    int cg = i & 31;
    float4 a = ((const float4*)v)[i];
    float4 r = ((const float4*)xin)[i];
    float4 sc = ((const float4*)scale)[cg];
    float4 sh = ((const float4*)shift)[cg];
    a.x = fmaxf(fmaf(a.x, sc.x, sh.x) + r.x, 0.f);
    a.y = fmaxf(fmaf(a.y, sc.y, sh.y) + r.y, 0.f);
    a.z = fmaxf(fmaf(a.z, sc.z, sh.z) + r.z, 0.f);
    a.w = fmaxf(fmaf(a.w, sc.w, sh.w) + r.w, 0.f);
    ((float4*)outv)[i] = a;
}

// ---------------------------------------------------------------------------
extern "C" void kernel_launch(void* const* d_in, const int* in_sizes, int n_in,
                              void* d_out, int out_size, void* d_ws, size_t ws_size,
                              hipStream_t stream) {
    const float* x      = (const float*)d_in[0];
    const float* W1     = (const float*)d_in[1];
    // b1/b2 cancel exactly inside BatchNorm (per-channel constant shift)
    const float* W2     = (const float*)d_in[3];
    const float* gamma2 = (const float*)d_in[5];
    const float* beta2  = (const float*)d_in[6];
    const int*   ei     = (const int*)d_in[7];    // [2, E] int32
    const int*   srcI   = ei;
    const int*   dstI   = ei + EDGES;
    float* out = (float*)d_out;

    char* ws = (char*)d_ws;
    float* A        = (float*)(ws);                       // 51.2 MB
    float* B        = (float*)(ws + 51200000);            // 51.2 MB
    int*   degcnt   = (int*)  (ws + 102400000);           // 400 KB (aliased as cursor later)
    float* dinv     = (float*)(ws + 102800000);           // 400 KB
    int*   rowptr   = (int*)  (ws + 103200000);           // 400,004 B
    int*   srcs     = (int*)  (ws + 103600016);           // 6.4 MB
    int*   blocksum = (int*)  (ws + 110000016);           // 391*4 B
    float* gsum     = (float*)(ws + 110002048);           // 512 B
    float* gsumsq   = gsum + 128;
    float* scale    = gsum + 256;
    float* shift    = gsum + 384;
    int*   cursor   = degcnt;   // degcnt dead after dinv+scan1; reuse as cursor

    const int ELEM4_BLOCKS = (N_NODES * 32) / 256;        // 12500
    const int GEMM_BLOCKS  = N_NODES / 32;                // 3125
    const int NODE2_BLOCKS = N_NODES / 2;                 // 50000

    // ---- CSR build (once, reused by both convs) ----
    hipMemsetAsync(degcnt, 0, N_NODES * sizeof(int), stream);
    deg_kernel<<<EDGES / 256, 256, 0, stream>>>(dstI, degcnt);
    dinv_kernel<<<SCAN_NB, 256, 0, stream>>>(degcnt, dinv);
    scan1<<<SCAN_NB, 256, 0, stream>>>(degcnt, rowptr, blocksum);
    scan2<<<1, 512, 0, stream>>>(blocksum);
    scan3<<<SCAN_NB, 256, 0, stream>>>(rowptr, blocksum, cursor);
    bucket_kernel<<<EDGES / 256, 256, 0, stream>>>(srcI, dstI, cursor, srcs);

    // ---- conv1 ----
    gemm128<<<GEMM_BLOCKS, 256, 0, stream>>>(x, W1, dinv, A);            // hs1 -> A
    gather_agg<<<NODE2_BLOCKS, 256, 0, stream>>>(A, srcs, rowptr, dinv, B); // agg1 -> B
    hipMemsetAsync(gsum, 0, 256 * sizeof(float), stream);
    bn_stats<<<256, 256, 0, stream>>>(B, gsum, gsumsq);
    bn_final<<<1, 128, 0, stream>>>(gsum, gsumsq, gamma2, beta2, scale, shift);
    bn_apply_relu<<<ELEM4_BLOCKS, 256, 0, stream>>>(B, scale, shift, A);  // x1 -> A

    // ---- conv2 ----
    gemm128<<<GEMM_BLOCKS, 256, 0, stream>>>(A, W2, dinv, B);            // hs2 -> B
    gather_agg<<<NODE2_BLOCKS, 256, 0, stream>>>(B, srcs, rowptr, dinv, A); // agg2 -> A
    hipMemsetAsync(gsum, 0, 256 * sizeof(float), stream);
    bn_stats<<<256, 256, 0, stream>>>(A, gsum, gsumsq);
    bn_final<<<1, 128, 0, stream>>>(gsum, gsumsq, gamma2, beta2, scale, shift);
    bn_apply_res_relu<<<ELEM4_BLOCKS, 256, 0, stream>>>(A, scale, shift, x, out);
}

// Round 3
// 668.508 us; speedup vs baseline: 2.7922x; 1.2790x over previous
//
#include <hip/hip_runtime.h>

#define N_NODES 100000
#define EDGES   1600000
#define CH      128
#define BN_EPS  1e-5f
#define SCAN_NB ((N_NODES + 255) / 256)   // 391 scan blocks

typedef __attribute__((ext_vector_type(8))) __bf16 bf16x8;
typedef __attribute__((ext_vector_type(2))) __bf16 bf16x2;
typedef __attribute__((ext_vector_type(4))) float  f32x4;

// ---------------------------------------------------------------------------
// CSR build
// ---------------------------------------------------------------------------
__global__ __launch_bounds__(256) void deg_kernel(const int* __restrict__ dst,
                                                  int* __restrict__ degcnt) {
    int e = blockIdx.x * 256 + threadIdx.x;
    if (e < EDGES) atomicAdd(&degcnt[dst[e]], 1);
}

__global__ __launch_bounds__(256) void dinv_kernel(const int* __restrict__ degcnt,
                                                   float* __restrict__ dinv) {
    int n = blockIdx.x * 256 + threadIdx.x;
    if (n < N_NODES) dinv[n] = rsqrtf((float)degcnt[n] + 1.0f);
}

__global__ __launch_bounds__(256) void scan1(const int* __restrict__ degcnt,
                                             int* __restrict__ rowptr,
                                             int* __restrict__ blocksum) {
    __shared__ int sh[2][256];
    int t = threadIdx.x;
    int i = blockIdx.x * 256 + t;
    int v = (i < N_NODES) ? degcnt[i] : 0;
    sh[0][t] = v;
    __syncthreads();
    int pp = 0;
    #pragma unroll
    for (int off = 1; off < 256; off <<= 1) {
        int val = sh[pp][t] + ((t >= off) ? sh[pp][t - off] : 0);
        sh[1 - pp][t] = val;
        pp = 1 - pp;
        __syncthreads();
    }
    int incl = sh[pp][t];
    if (i < N_NODES) rowptr[i] = incl - v;
    if (t == 255) blocksum[blockIdx.x] = incl;
}

__global__ __launch_bounds__(512) void scan2(int* __restrict__ blocksum) {
    __shared__ int sh[2][512];
    int t = threadIdx.x;
    int v = (t < SCAN_NB) ? blocksum[t] : 0;
    sh[0][t] = v;
    __syncthreads();
    int pp = 0;
    #pragma unroll
    for (int off = 1; off < 512; off <<= 1) {
        int val = sh[pp][t] + ((t >= off) ? sh[pp][t - off] : 0);
        sh[1 - pp][t] = val;
        pp = 1 - pp;
        __syncthreads();
    }
    if (t < SCAN_NB) blocksum[t] = sh[pp][t] - v;
}

__global__ __launch_bounds__(256) void scan3(int* __restrict__ rowptr,
                                             const int* __restrict__ blocksum,
                                             int* __restrict__ cursor) {
    int i = blockIdx.x * 256 + threadIdx.x;
    if (i < N_NODES) {
        int v = rowptr[i] + blocksum[blockIdx.x];
        rowptr[i] = v;
        cursor[i] = v;
    }
    if (i == N_NODES - 1) rowptr[N_NODES] = EDGES;
}

__global__ __launch_bounds__(256) void bucket_kernel(const int* __restrict__ src,
                                                     const int* __restrict__ dst,
                                                     int* __restrict__ cursor,
                                                     int* __restrict__ srcs) {
    int e = blockIdx.x * 256 + threadIdx.x;
    if (e < EDGES) {
        int pos = atomicAdd(&cursor[dst[e]], 1);
        srcs[pos] = src[e];
    }
}

// ---------------------------------------------------------------------------
// W transpose + bf16 convert: Wt[n][k] = bf16(W[k][n])  (B-fragment layout)
// ---------------------------------------------------------------------------
__global__ __launch_bounds__(256) void wtrans(const float* __restrict__ W,
                                              __bf16* __restrict__ Wt) {
    int idx = blockIdx.x * 256 + threadIdx.x;   // 16384 elements
    int n = idx >> 7, k = idx & 127;
    Wt[idx] = (__bf16)W[k * 128 + n];
}

// ---------------------------------------------------------------------------
// MFMA bf16 GEMM: hs[n][c] = bf16( dinv[n] * sum_k Aval(n,k) * W[k][c] )
//   BN_PRO=false: Aval = A[n][k]                 (layer 1, A = x fp32)
//   BN_PRO=true : Aval = relu(A[n][k]*scale[k]+shift[k])   (fused BN1-apply)
// One wave computes a 16-row x 128-col strip via 8 col-tiles of 16x16x32.
// A-frag lane layout: A[m=lane&15][k=quad*8+j]; B-frag from Wt[n][k] (same).
// C/D: col=lane&15, row=quad*4+reg.
// ---------------------------------------------------------------------------
template <bool BN_PRO>
__global__ __launch_bounds__(256) void gemm_mfma(const float* __restrict__ A,
                                                 const __bf16* __restrict__ Wt,
                                                 const float* __restrict__ dinv,
                                                 const float* __restrict__ scale,
                                                 const float* __restrict__ shift,
                                                 __bf16* __restrict__ hs) {
    const int wave = threadIdx.x >> 6;
    const int rt = blockIdx.x * 4 + wave;          // row-tile index, 6250 total
    if (rt >= N_NODES / 16) return;
    const int lane = threadIdx.x & 63;
    const int ln = lane & 15;
    const int quad = lane >> 4;

    const int arow = rt * 16 + ln;

    f32x4 acc[8];
    #pragma unroll
    for (int ct = 0; ct < 8; ++ct) acc[ct] = (f32x4){0.f, 0.f, 0.f, 0.f};

    #pragma unroll
    for (int k0 = 0; k0 < 128; k0 += 32) {
        const int k = k0 + quad * 8;
        float4 a0 = *(const float4*)(A + (size_t)arow * CH + k);
        float4 a1 = *(const float4*)(A + (size_t)arow * CH + k + 4);
        if (BN_PRO) {
            float4 sc0 = *(const float4*)(scale + k);
            float4 sc1 = *(const float4*)(scale + k + 4);
            float4 sh0 = *(const float4*)(shift + k);
            float4 sh1 = *(const float4*)(shift + k + 4);
            a0.x = fmaxf(fmaf(a0.x, sc0.x, sh0.x), 0.f);
            a0.y = fmaxf(fmaf(a0.y, sc0.y, sh0.y), 0.f);
            a0.z = fmaxf(fmaf(a0.z, sc0.z, sh0.z), 0.f);
            a0.w = fmaxf(fmaf(a0.w, sc0.w, sh0.w), 0.f);
            a1.x = fmaxf(fmaf(a1.x, sc1.x, sh1.x), 0.f);
            a1.y = fmaxf(fmaf(a1.y, sc1.y, sh1.y), 0.f);
            a1.z = fmaxf(fmaf(a1.z, sc1.z, sh1.z), 0.f);
            a1.w = fmaxf(fmaf(a1.w, sc1.w, sh1.w), 0.f);
        }
        bf16x8 af;
        af[0] = (__bf16)a0.x; af[1] = (__bf16)a0.y;
        af[2] = (__bf16)a0.z; af[3] = (__bf16)a0.w;
        af[4] = (__bf16)a1.x; af[5] = (__bf16)a1.y;
        af[6] = (__bf16)a1.z; af[7] = (__bf16)a1.w;
        #pragma unroll
        for (int ct = 0; ct < 8; ++ct) {
            bf16x8 bfrag = *(const bf16x8*)(Wt + (size_t)(ct * 16 + ln) * CH + k);
            acc[ct] = __builtin_amdgcn_mfma_f32_16x16x32_bf16(af, bfrag, acc[ct], 0, 0, 0);
        }
    }

    #pragma unroll
    for (int r = 0; r < 4; ++r) {
        const int row_r = rt * 16 + quad * 4 + r;
        const float dr = dinv[row_r];
        __bf16* orow = hs + (size_t)row_r * CH + ln;
        #pragma unroll
        for (int ct = 0; ct < 8; ++ct)
            orow[ct * 16] = (__bf16)(acc[ct][r] * dr);
    }
}

// ---------------------------------------------------------------------------
// pull-gather (bf16 hs): agg[n][c] = dinv[n]*(hs[n][c] + sum_j hs[srcs[j]][c])
// 64 threads per node (2 channels each, dword loads), 4 nodes per block
// ---------------------------------------------------------------------------
__global__ __launch_bounds__(256) void gather_agg(const __bf16* __restrict__ hs,
                                                  const int* __restrict__ srcs,
                                                  const int* __restrict__ rowptr,
                                                  const float* __restrict__ dinv,
                                                  float* __restrict__ agg) {
    int n = blockIdx.x * 4 + (threadIdx.x >> 6);
    int c2 = threadIdx.x & 63;                    // channels 2*c2, 2*c2+1
    int beg = rowptr[n];
    int end = rowptr[n + 1];
    const bf16x2* hp = (const bf16x2*)hs;         // index: node*64 + c2
    bf16x2 sv = hp[(size_t)n * 64 + c2];
    float ax = (float)sv[0], ay = (float)sv[1];
    int j = beg;
    for (; j + 4 <= end; j += 4) {
        int s0 = srcs[j + 0];
        int s1 = srcs[j + 1];
        int s2 = srcs[j + 2];
        int s3 = srcs[j + 3];
        bf16x2 v0 = hp[(size_t)s0 * 64 + c2];
        bf16x2 v1 = hp[(size_t)s1 * 64 + c2];
        bf16x2 v2 = hp[(size_t)s2 * 64 + c2];
        bf16x2 v3 = hp[(size_t)s3 * 64 + c2];
        ax += ((float)v0[0] + (float)v1[0]) + ((float)v2[0] + (float)v3[0]);
        ay += ((float)v0[1] + (float)v1[1]) + ((float)v2[1] + (float)v3[1]);
    }
    for (; j < end; ++j) {
        bf16x2 v = hp[(size_t)srcs[j] * 64 + c2];
        ax += (float)v[0];
        ay += (float)v[1];
    }
    float d = dinv[n];
    float2 o; o.x = ax * d; o.y = ay * d;
    ((float2*)agg)[(size_t)n * 64 + c2] = o;
}

// ---------------------------------------------------------------------------
// BatchNorm pieces
// ---------------------------------------------------------------------------
__global__ __launch_bounds__(256) void bn_stats(const float* __restrict__ v,
                                                float* __restrict__ gsum,
                                                float* __restrict__ gsumsq) {
    int c = threadIdx.x & 127;
    int half = threadIdx.x >> 7;
    float s = 0.f, ss = 0.f;
    for (int n = blockIdx.x * 2 + half; n < N_NODES; n += gridDim.x * 2) {
        float x = v[(size_t)n * CH + c];
        s += x; ss += x * x;
    }
    atomicAdd(&gsum[c], s);
    atomicAdd(&gsumsq[c], ss);
}

__global__ void bn_final(const float* __restrict__ gsum,
                         const float* __restrict__ gsumsq,
                         const float* __restrict__ gamma,
                         const float* __restrict__ beta,
                         float* __restrict__ scale,
                         float* __restrict__ shift) {
    int c = threadIdx.x;
    const float invN = 1.0f / (float)N_NODES;
    float mu = gsum[c] * invN;
    float var = gsumsq[c] * invN - mu * mu;
    float sc = gamma[c] * rsqrtf(var + BN_EPS);
    scale[c] = sc;
    shift[c] = beta[c] - mu * sc;
}

// final epilogue: out = relu(v*scale + shift + x)
__global__ __launch_bounds__(256) void bn_apply_res_relu(const float* __restrict__ v,
                                                         const float* __restrict__ scale,
                                                         const float* __restrict__ shift,
                                                         const float* __restrict__ xin,
                                                         float* __restrict__ outv) {
    int i = blockIdx.x * 256 + threadIdx.x;
    int cg = i & 31;
    float4 a = ((const float4*)v)[i];
    float4 r = ((const float4*)xin)[i];
    float4 sc = ((const float4*)scale)[cg];
    float4 sh = ((const float4*)shift)[cg];
    a.x = fmaxf(fmaf(a.x, sc.x, sh.x) + r.x, 0.f);
    a.y = fmaxf(fmaf(a.y, sc.y, sh.y) + r.y, 0.f);
    a.z = fmaxf(fmaf(a.z, sc.z, sh.z) + r.z, 0.f);
    a.w = fmaxf(fmaf(a.w, sc.w, sh.w) + r.w, 0.f);
    ((float4*)outv)[i] = a;
}

// ---------------------------------------------------------------------------
extern "C" void kernel_launch(void* const* d_in, const int* in_sizes, int n_in,
                              void* d_out, int out_size, void* d_ws, size_t ws_size,
                              hipStream_t stream) {
    const float* x      = (const float*)d_in[0];
    const float* W1     = (const float*)d_in[1];
    // b1/b2 cancel exactly inside BatchNorm (per-channel constant shift)
    const float* W2     = (const float*)d_in[3];
    const float* gamma2 = (const float*)d_in[5];
    const float* beta2  = (const float*)d_in[6];
    const int*   ei     = (const int*)d_in[7];    // [2, E] int32
    const int*   srcI   = ei;
    const int*   dstI   = ei + EDGES;
    float* out = (float*)d_out;

    char* ws = (char*)d_ws;
    float*  agg      = (float*) (ws);                      // 51.2 MB  (agg1 then agg2)
    __bf16* hs       = (__bf16*)(ws + 51200000);           // 25.6 MB  (hs1 then hs2)
    int*    degcnt   = (int*)   (ws + 76800000);           // 400 KB (reused as cursor)
    float*  dinv     = (float*) (ws + 77200000);           // 400 KB
    int*    rowptr   = (int*)   (ws + 77600000);           // 400,016 B
    int*    srcs     = (int*)   (ws + 78000016);           // 6.4 MB
    int*    blocksum = (int*)   (ws + 84400016);           // pad to 84,401,600
    __bf16* Wt1      = (__bf16*)(ws + 84401600);           // 32 KB
    __bf16* Wt2      = (__bf16*)(ws + 84434368);           // 32 KB
    float*  gsum     = (float*) (ws + 84467136);
    float*  gsumsq   = gsum + 128;
    float*  scale1   = gsum + 256;
    float*  shift1   = gsum + 384;
    float*  scale2   = gsum + 512;
    float*  shift2   = gsum + 640;
    int*    cursor   = degcnt;

    const int ELEM4_BLOCKS = (N_NODES * 32) / 256;        // 12500
    const int GEMM_BLOCKS  = (N_NODES / 16 + 3) / 4;      // 1563 (6250 wave-tiles)
    const int NODE4_BLOCKS = N_NODES / 4;                 // 25000

    // ---- CSR build + weight prep ----
    hipMemsetAsync(degcnt, 0, N_NODES * sizeof(int), stream);
    deg_kernel<<<EDGES / 256, 256, 0, stream>>>(dstI, degcnt);
    dinv_kernel<<<SCAN_NB, 256, 0, stream>>>(degcnt, dinv);
    scan1<<<SCAN_NB, 256, 0, stream>>>(degcnt, rowptr, blocksum);
    scan2<<<1, 512, 0, stream>>>(blocksum);
    scan3<<<SCAN_NB, 256, 0, stream>>>(rowptr, blocksum, cursor);
    bucket_kernel<<<EDGES / 256, 256, 0, stream>>>(srcI, dstI, cursor, srcs);
    wtrans<<<64, 256, 0, stream>>>(W1, Wt1);
    wtrans<<<64, 256, 0, stream>>>(W2, Wt2);

    // ---- conv1 ----
    gemm_mfma<false><<<GEMM_BLOCKS, 256, 0, stream>>>(x, Wt1, dinv, nullptr, nullptr, hs);
    gather_agg<<<NODE4_BLOCKS, 256, 0, stream>>>(hs, srcs, rowptr, dinv, agg);
    hipMemsetAsync(gsum, 0, 256 * sizeof(float), stream);
    bn_stats<<<256, 256, 0, stream>>>(agg, gsum, gsumsq);
    bn_final<<<1, 128, 0, stream>>>(gsum, gsumsq, gamma2, beta2, scale1, shift1);

    // ---- conv2 (BN1-apply + relu fused into A-fragment load) ----
    gemm_mfma<true><<<GEMM_BLOCKS, 256, 0, stream>>>(agg, Wt2, dinv, scale1, shift1, hs);
    gather_agg<<<NODE4_BLOCKS, 256, 0, stream>>>(hs, srcs, rowptr, dinv, agg);
    hipMemsetAsync(gsum, 0, 256 * sizeof(float), stream);
    bn_stats<<<256, 256, 0, stream>>>(agg, gsum, gsumsq);
    bn_final<<<1, 128, 0, stream>>>(gsum, gsumsq, gamma2, beta2, scale2, shift2);
    bn_apply_res_relu<<<ELEM4_BLOCKS, 256, 0, stream>>>(agg, scale2, shift2, x, out);
}